// Round 21
// baseline (118.931 us; speedup 1.0000x reference)
//
#include <hip/hip_runtime.h>
#include <hip/hip_bf16.h>

// Shapes fixed by setup_inputs(): B=2, C=128, H=256, W=448, stride=1.
#define BB 2
#define CC 128
#define HH 256
#define WW 448
#define KK 49
#define HWSZ (HH * WW)

#define TWT_BYTES ((size_t)BB * HH * WW * CC * 2)  // 58,720,256
#define DESC_BYTES ((size_t)BB * HWSZ * 32)        // 7,340,032

typedef __attribute__((ext_vector_type(8))) short bf16x8;
typedef __attribute__((ext_vector_type(4))) float f32x4;
typedef __attribute__((ext_vector_type(8))) unsigned short u16x8;

static __device__ __forceinline__ short f2bf(float v) {
  __hip_bfloat16 h = __float2bfloat16(v);
  return *reinterpret_cast<short*>(&h);
}
static __device__ __forceinline__ float bf2f(unsigned short u) {
  unsigned int x = ((unsigned int)u) << 16;
  return __uint_as_float(x);
}

// ---------------- Kernel T: transpose tenTwo [c][p] f32 -> two_t [p][c] bf16
__global__ __launch_bounds__(256) void transpose_kernel(
    const float* __restrict__ two, __hip_bfloat16* __restrict__ two_t) {
  __shared__ float lds[128 * 33];
  int bid = blockIdx.x;  // BB * 3584 = 7168
  int b = bid / (HWSZ / 32);
  int tile = bid - b * (HWSZ / 32);
  int P0 = tile * 32;

  const float* src = two + (size_t)b * CC * HWSZ + P0;
  int t = threadIdx.x;
  int bc = t >> 3;  // 0..31
  int f = t & 7;    // 0..7
#pragma unroll
  for (int k = 0; k < 4; ++k) {
    int c = bc + k * 32;
    float4 v = *(const float4*)(src + (size_t)c * HWSZ + f * 4);
    float* d = &lds[c * 33 + f * 4];
    d[0] = v.x; d[1] = v.y; d[2] = v.z; d[3] = v.w;
  }
  __syncthreads();

  int q = t & 7;    // c-chunk of 16
  int pl = t >> 3;  // 0..31 pixel
  int cs = q * 16;
  u16x8 pk0, pk1;
#pragma unroll
  for (int j = 0; j < 8; ++j)
    pk0[j] = (unsigned short)f2bf(lds[(cs + j) * 33 + pl]);
#pragma unroll
  for (int j = 0; j < 8; ++j)
    pk1[j] = (unsigned short)f2bf(lds[(cs + 8 + j) * 33 + pl]);
  char* dst = (char*)two_t + ((size_t)((size_t)b * HWSZ + P0 + pl) * CC + cs) * 2;
  *(u16x8*)dst = pk0;
  *(u16x8*)(dst + 16) = pk1;
}

// ---------------- Kernel F: flow -> per-pixel gather descriptors ------------
__global__ __launch_bounds__(256) void flowprep(
    const float* __restrict__ flow, float* __restrict__ desc) {
  int idx = blockIdx.x * 256 + threadIdx.x;  // BB*HWSZ = 229376
  int x = idx % WW;
  int y = (idx / WW) % HH;
  int b = idx / HWSZ;

  float fx = flow[(size_t)(b * 2 + 0) * HWSZ + y * WW + x] * 2.5f;
  float fy = flow[(size_t)(b * 2 + 1) * HWSZ + y * WW + x] * 2.5f;
  float px = (float)x + fx;
  float py = (float)y + fy;
  float x0f = floorf(px), y0f = floorf(py);
  int x0 = (int)x0f, y0 = (int)y0f;
  int x1 = x0 + 1, y1 = y0 + 1;
  float wx1 = px - x0f, wx0 = 1.0f - wx1;
  float wy1 = py - y0f, wy0 = 1.0f - wy1;
  bool vx0 = (x0 >= 0) && (x0 < WW);
  bool vx1 = (x1 >= 0) && (x1 < WW);
  bool vy0 = (y0 >= 0) && (y0 < HH);
  bool vy1 = (y1 >= 0) && (y1 < HH);
  float w00 = (vx0 && vy0) ? wx0 * wy0 : 0.0f;
  float w01 = (vx1 && vy0) ? wx1 * wy0 : 0.0f;
  float w10 = (vx0 && vy1) ? wx0 * wy1 : 0.0f;
  float w11 = (vx1 && vy1) ? wx1 * wy1 : 0.0f;
  int cx0 = min(max(x0, 0), WW - 1);
  int cx1 = min(max(x1, 0), WW - 1);
  int cy0 = min(max(y0, 0), HH - 1);
  int cy1 = min(max(y1, 0), HH - 1);

  float* d = desc + (size_t)idx * 8;
  *(float4*)d = make_float4(w00, w01, w10, w11);
  int4 o = make_int4(cy0 * WW + cx0, cy0 * WW + cx1, cy1 * WW + cx0,
                     cy1 * WW + cx1);
  *(int4*)(d + 4) = o;
}

// ---------------- Kernel 2: FUSED backwarp + correlation via MFMA -----------
// R20 structure with software-pipelined staging: chunk groups {4,4,2}; group
// g+1's desc loads issue before group g's corner processing, so desc latency
// hides under corners. Named per-chunk desc regs (no dynamic indexing),
// sched_barrier fences stop the compiler re-sinking prefetches.
#define YTB 8
#define NROWS 14               // YTB + 6
#define NPOS 22
#define ROWCH (NPOS * 16)      // 352 16B-chunks per row
#define CHUNKS (NROWS * ROWCH) // 4928 chunks = 78,848 B

__global__ __launch_bounds__(512, 4) void corr_fused(
    const float* __restrict__ one, const __hip_bfloat16* __restrict__ two_t,
    const float* __restrict__ desc, float* __restrict__ out) {
  __shared__ uint4 ldsb[CHUNKS];

  int bid = blockIdx.x;                    // 1792 = 8 * 224
  int wg = (bid & 7) * 224 + (bid >> 3);   // XCD-chunked, bijective
  int b = wg / 896;
  int rem = wg - b * 896;
  int xt = rem >> 5;   // 0..27
  int yt = rem & 31;   // 0..31
  int ybase = yt * YTB;
  int X0 = xt * 16;
  int tid = threadIdx.x;
  int w = tid >> 6;   // wave 0..7
  int l = tid & 63;
  int lp = l & 15;
  int lg = l >> 4;
  int y = ybase + w;

  const char* tb = (const char*)two_t + (size_t)b * HWSZ * (CC * 2);
  const float* dbase = desc + (size_t)b * HWSZ * 8;

#define DESC_LOAD(K, WV, OV)                                  \
  {                                                           \
    int ci = tid + (K)*512;                                   \
    if (ci < CHUNKS) {                                        \
      int row = ci / ROWCH;                                   \
      int r2 = ci - row * ROWCH;                              \
      int p_ = r2 >> 4;                                       \
      int yy = ybase - 3 + row;                               \
      int x_ = X0 + p_ - 3;                                   \
      int yyc = min(max(yy, 0), HH - 1);                      \
      int xc = min(max(x_, 0), WW - 1);                       \
      const float* dp = dbase + (size_t)(yyc * WW + xc) * 8;  \
      WV = *(const float4*)dp;                                \
      OV = *(const int4*)(dp + 4);                            \
    }                                                         \
  }

#define CHUNK_PROC(K, WV, OV)                                              \
  {                                                                        \
    int ci = tid + (K)*512;                                                \
    if (ci < CHUNKS) {                                                     \
      int row = ci / ROWCH;                                                \
      int r2 = ci - row * ROWCH;                                           \
      int p_ = r2 >> 4;                                                    \
      int cw = r2 & 15;                                                    \
      int yy = ybase - 3 + row;                                            \
      int x_ = X0 + p_ - 3;                                                \
      bool vpix = (yy >= 0) && (yy < HH) && (x_ >= 0) && (x_ < WW);        \
      u16x8 ca = *(const u16x8*)(tb + (size_t)(OV).x * 256 + cw * 16);     \
      u16x8 cb = *(const u16x8*)(tb + (size_t)(OV).y * 256 + cw * 16);     \
      u16x8 cc = *(const u16x8*)(tb + (size_t)(OV).z * 256 + cw * 16);     \
      u16x8 cd = *(const u16x8*)(tb + (size_t)(OV).w * 256 + cw * 16);     \
      u16x8 pk;                                                            \
      _Pragma("unroll") for (int e = 0; e < 8; ++e) {                      \
        float v = (WV).x * bf2f((unsigned short)ca[e]) +                   \
                  (WV).y * bf2f((unsigned short)cb[e]) +                   \
                  (WV).z * bf2f((unsigned short)cc[e]) +                   \
                  (WV).w * bf2f((unsigned short)cd[e]);                    \
        pk[e] = (unsigned short)f2bf(v);                                   \
      }                                                                    \
      if (!vpix) pk = (u16x8){0, 0, 0, 0, 0, 0, 0, 0};                     \
      *(u16x8*)((char*)ldsb + ((ci * 16) ^ ((p_ & 15) << 4))) = pk;        \
    }                                                                      \
  }

  float4 wA0 = {}, wA1 = {}, wA2 = {}, wA3 = {};
  int4 oA0 = {}, oA1 = {}, oA2 = {}, oA3 = {};
  float4 wB0 = {}, wB1 = {}, wB2 = {}, wB3 = {};
  int4 oB0 = {}, oB1 = {}, oB2 = {}, oB3 = {};
  float4 wC0 = {}, wC1 = {};
  int4 oC0 = {}, oC1 = {};

  // G0 descs (chunks 0..3)
  DESC_LOAD(0, wA0, oA0) DESC_LOAD(1, wA1, oA1)
  DESC_LOAD(2, wA2, oA2) DESC_LOAD(3, wA3, oA3)
  __builtin_amdgcn_sched_barrier(0);
  // G1 descs in flight (chunks 4..7)
  DESC_LOAD(4, wB0, oB0) DESC_LOAD(5, wB1, oB1)
  DESC_LOAD(6, wB2, oB2) DESC_LOAD(7, wB3, oB3)
  __builtin_amdgcn_sched_barrier(0);
  // process G0 (desc latency for G1 hides under these 16 corner loads)
  CHUNK_PROC(0, wA0, oA0) CHUNK_PROC(1, wA1, oA1)
  CHUNK_PROC(2, wA2, oA2) CHUNK_PROC(3, wA3, oA3)
  __builtin_amdgcn_sched_barrier(0);
  // G2 descs in flight (chunks 8..9)
  DESC_LOAD(8, wC0, oC0) DESC_LOAD(9, wC1, oC1)
  __builtin_amdgcn_sched_barrier(0);
  // process G1
  CHUNK_PROC(4, wB0, oB0) CHUNK_PROC(5, wB1, oB1)
  CHUNK_PROC(6, wB2, oB2) CHUNK_PROC(7, wB3, oB3)
  __builtin_amdgcn_sched_barrier(0);
  // process G2
  CHUNK_PROC(8, wC0, oC0) CHUNK_PROC(9, wC1, oC1)

  // ---- A fragments ---------------------------------------------------------
  const float* Abase = one + ((size_t)(b * CC) * HH + y) * WW + X0 + lp;
  bf16x8 afr[4];
#pragma unroll
  for (int t = 0; t < 4; ++t)
#pragma unroll
    for (int j = 0; j < 8; ++j)
      afr[t][j] = f2bf(Abase[(size_t)(t * 32 + lg * 8 + j) * HWSZ]);

  __syncthreads();  // staged tile visible

  // ---- compute: pure ds_read_b128 + MFMA (R14 verbatim) -------------------
  int p1 = (lp + 16 < 21) ? (lp + 16) : 21;
  int cosw0[4], cosw1[4];
#pragma unroll
  for (int t = 0; t < 4; ++t) {
    int co = t * 64 + lg * 16;
    cosw0[t] = co ^ ((lp & 15) << 4);
    cosw1[t] = co ^ ((p1 & 15) << 4);
  }

  f32x4 acc[7][2] = {};
#pragma unroll
  for (int dj = 0; dj < 7; ++dj) {
    int rl = w + dj;  // LDS row for yy = y + dj - 3
    int b0 = (rl * NPOS + lp) << 8;
    int b1 = (rl * NPOS + p1) << 8;
#pragma unroll
    for (int t = 0; t < 4; ++t) {
      bf16x8 v0 = *(const bf16x8*)((const char*)ldsb + (b0 + cosw0[t]));
      bf16x8 v1 = *(const bf16x8*)((const char*)ldsb + (b1 + cosw1[t]));
      acc[dj][0] = __builtin_amdgcn_mfma_f32_16x16x32_bf16(afr[t], v0,
                                                           acc[dj][0], 0, 0, 0);
      acc[dj][1] = __builtin_amdgcn_mfma_f32_16x16x32_bf16(afr[t], v1,
                                                           acc[dj][1], 0, 0, 0);
    }
  }

  // ---- Epilogue: LDS transpose -> dense stores (R14 verbatim) -------------
  __syncthreads();  // all ds_reads of ldsb done; safe to reuse as scratch
  float* sc = (float*)ldsb;  // [49][8][16] f32, col-swizzled by +k (mod 16)
#pragma unroll
  for (int dj = 0; dj < 7; ++dj) {
#pragma unroll
    for (int nt = 0; nt < 2; ++nt) {
      int post = lp + 16 * nt;
#pragma unroll
      for (int r = 0; r < 4; ++r) {
        int xlc = 4 * lg + r;
        int di = post - xlc;
        if (di >= 0 && di <= 6) {
          int k = dj * 7 + di;
          sc[k * 128 + w * 16 + ((xlc + k) & 15)] = acc[dj][nt][r];
        }
      }
    }
  }
  __syncthreads();

  float* ob = out + (size_t)(b * KK) * HWSZ + (size_t)ybase * WW + X0;
#pragma unroll
  for (int i = 0; i < 13; ++i) {
    int e = tid + i * 512;
    if (e < KK * 128) {
      int k = e >> 7;
      int yr = (e >> 4) & 7;
      int px = e & 15;
      float v = sc[k * 128 + yr * 16 + ((px + k) & 15)] * (1.0f / 128.0f);
      v = (v > 0.0f) ? v : 0.1f * v;
      ob[(size_t)k * HWSZ + yr * WW + px] = v;
    }
  }
#undef DESC_LOAD
#undef CHUNK_PROC
}

// ---------------- launch ----------------------------------------------------
extern "C" void kernel_launch(void* const* d_in, const int* in_sizes, int n_in,
                              void* d_out, int out_size, void* d_ws,
                              size_t ws_size, hipStream_t stream) {
  const float* tenOne = (const float*)d_in[0];
  const float* tenTwo = (const float*)d_in[1];
  const float* tenFlow = (const float*)d_in[2];

  __hip_bfloat16* two_t = (__hip_bfloat16*)d_ws;    // 58.7 MB
  float* desc = (float*)((char*)d_ws + TWT_BYTES);  // 7.3 MB

  transpose_kernel<<<BB * (HWSZ / 32), 256, 0, stream>>>(tenTwo, two_t);
  flowprep<<<BB * HWSZ / 256, 256, 0, stream>>>(tenFlow, desc);
  corr_fused<<<1792, 512, 0, stream>>>(tenOne, two_t, desc, (float*)d_out);
}

// Round 22
// 114.332 us; speedup vs baseline: 1.0402x; 1.0402x over previous
//
#include <hip/hip_runtime.h>
#include <hip/hip_bf16.h>

// Shapes fixed by setup_inputs(): B=2, C=128, H=256, W=448, stride=1.
#define BB 2
#define CC 128
#define HH 256
#define WW 448
#define KK 49
#define HWSZ (HH * WW)

#define TWT_BYTES ((size_t)BB * HH * WW * CC * 2)  // 58,720,256

typedef __attribute__((ext_vector_type(8))) short bf16x8;
typedef __attribute__((ext_vector_type(4))) float f32x4;
typedef __attribute__((ext_vector_type(8))) unsigned short u16x8;

static __device__ __forceinline__ short f2bf(float v) {
  __hip_bfloat16 h = __float2bfloat16(v);
  return *reinterpret_cast<short*>(&h);
}
static __device__ __forceinline__ float bf2f(unsigned short u) {
  unsigned int x = ((unsigned int)u) << 16;
  return __uint_as_float(x);
}

// ---------------- Kernel T: transpose tenTwo [c][p] f32 -> two_t [p][c] bf16
__global__ __launch_bounds__(256) void transpose_kernel(
    const float* __restrict__ two, __hip_bfloat16* __restrict__ two_t) {
  __shared__ float lds[128 * 33];
  int bid = blockIdx.x;  // BB * 3584 = 7168
  int b = bid / (HWSZ / 32);
  int tile = bid - b * (HWSZ / 32);
  int P0 = tile * 32;

  const float* src = two + (size_t)b * CC * HWSZ + P0;
  int t = threadIdx.x;
  int bc = t >> 3;  // 0..31
  int f = t & 7;    // 0..7
#pragma unroll
  for (int k = 0; k < 4; ++k) {
    int c = bc + k * 32;
    float4 v = *(const float4*)(src + (size_t)c * HWSZ + f * 4);
    float* d = &lds[c * 33 + f * 4];
    d[0] = v.x; d[1] = v.y; d[2] = v.z; d[3] = v.w;
  }
  __syncthreads();

  int q = t & 7;    // c-chunk of 16
  int pl = t >> 3;  // 0..31 pixel
  int cs = q * 16;
  u16x8 pk0, pk1;
#pragma unroll
  for (int j = 0; j < 8; ++j)
    pk0[j] = (unsigned short)f2bf(lds[(cs + j) * 33 + pl]);
#pragma unroll
  for (int j = 0; j < 8; ++j)
    pk1[j] = (unsigned short)f2bf(lds[(cs + 8 + j) * 33 + pl]);
  char* dst = (char*)two_t + ((size_t)((size_t)b * HWSZ + P0 + pl) * CC + cs) * 2;
  *(u16x8*)dst = pk0;
  *(u16x8*)(dst + 16) = pk1;
}

// ---------------- Kernel 2: FUSED backwarp + correlation via MFMA -----------
// R14 tiling/compute/epilogue (bench-verified), staging GATHERS the warped
// tile directly from two_t using flow: per chunk (row,pos,cw16), 16 lanes
// share one warped pixel -> flow read is lane-uniform, 4 corner reads are
// 256B dense per corner, blend in f32, ds_write with the 4-bit XOR swizzle.
// No wt intermediate; two_t (59MB) is L3-resident for the re-gather.
#define YTB 8
#define NROWS 14               // YTB + 6
#define NPOS 22
#define ROWCH (NPOS * 16)      // 352 16B-chunks per row
#define CHUNKS (NROWS * ROWCH) // 4928 chunks = 78,848 B

__global__ __launch_bounds__(512, 2) void corr_fused(
    const float* __restrict__ one, const __hip_bfloat16* __restrict__ two_t,
    const float* __restrict__ flow, float* __restrict__ out) {
  __shared__ uint4 ldsb[CHUNKS];

  int bid = blockIdx.x;                    // 1792 = 8 * 224
  int wg = (bid & 7) * 224 + (bid >> 3);   // XCD-chunked, bijective
  int b = wg / 896;
  int rem = wg - b * 896;
  int xt = rem >> 5;   // 0..27
  int yt = rem & 31;   // 0..31
  int ybase = yt * YTB;
  int X0 = xt * 16;
  int tid = threadIdx.x;
  int w = tid >> 6;   // wave 0..7
  int l = tid & 63;
  int lp = l & 15;
  int lg = l >> 4;
  int y = ybase + w;

  const char* tb = (const char*)two_t + (size_t)b * HWSZ * (CC * 2);
  const float* fxp = flow + (size_t)(b * 2 + 0) * HWSZ;
  const float* fyp = flow + (size_t)(b * 2 + 1) * HWSZ;

  // ---- fused gather-staging: warp the B tile straight into LDS ------------
#pragma unroll
  for (int k = 0; k < 10; ++k) {
    int ci = tid + k * 512;
    if (ci < CHUNKS) {
      int row = ci / ROWCH;
      int r2 = ci - row * ROWCH;
      int p = r2 >> 4;   // pos 0..21
      int cw = r2 & 15;  // 16B channel chunk
      int yy = ybase - 3 + row;   // warped-source row
      int x = X0 + p - 3;         // warped-source col
      bool vpix = (yy >= 0) && (yy < HH) && (x >= 0) && (x < WW);
      int yyc = min(max(yy, 0), HH - 1);
      int xc = min(max(x, 0), WW - 1);
      float fx = fxp[yyc * WW + xc] * 2.5f;  // lane-uniform per 16 lanes
      float fy = fyp[yyc * WW + xc] * 2.5f;
      float pxf = (float)x + fx;
      float pyf = (float)yy + fy;
      float x0f = floorf(pxf), y0f = floorf(pyf);
      int x0 = (int)x0f, y0 = (int)y0f;
      int x1 = x0 + 1, y1 = y0 + 1;
      float wx1 = pxf - x0f, wx0 = 1.0f - wx1;
      float wy1 = pyf - y0f, wy0 = 1.0f - wy1;
      float gate = vpix ? 1.0f : 0.0f;
      wy0 *= gate;
      wy1 *= gate;
      bool vx0 = (x0 >= 0) && (x0 < WW);
      bool vx1 = (x1 >= 0) && (x1 < WW);
      bool vy0 = (y0 >= 0) && (y0 < HH);
      bool vy1 = (y1 >= 0) && (y1 < HH);
      float w00 = (vx0 && vy0) ? wx0 * wy0 : 0.0f;
      float w01 = (vx1 && vy0) ? wx1 * wy0 : 0.0f;
      float w10 = (vx0 && vy1) ? wx0 * wy1 : 0.0f;
      float w11 = (vx1 && vy1) ? wx1 * wy1 : 0.0f;
      int cx0 = min(max(x0, 0), WW - 1);
      int cx1 = min(max(x1, 0), WW - 1);
      int cy0 = min(max(y0, 0), HH - 1);
      int cy1 = min(max(y1, 0), HH - 1);

      u16x8 ca = *(const u16x8*)(tb + ((size_t)cy0 * WW + cx0) * 256 + cw * 16);
      u16x8 cb = *(const u16x8*)(tb + ((size_t)cy0 * WW + cx1) * 256 + cw * 16);
      u16x8 cc = *(const u16x8*)(tb + ((size_t)cy1 * WW + cx0) * 256 + cw * 16);
      u16x8 cd = *(const u16x8*)(tb + ((size_t)cy1 * WW + cx1) * 256 + cw * 16);

      u16x8 pk;
#pragma unroll
      for (int e = 0; e < 8; ++e) {
        float v = w00 * bf2f((unsigned short)ca[e]) +
                  w01 * bf2f((unsigned short)cb[e]) +
                  w10 * bf2f((unsigned short)cc[e]) +
                  w11 * bf2f((unsigned short)cd[e]);
        pk[e] = (unsigned short)f2bf(v);
      }
      *(u16x8*)((char*)ldsb + ((ci * 16) ^ ((p & 15) << 4))) = pk;
    }
  }

  // ---- A fragments ---------------------------------------------------------
  const float* Abase = one + ((size_t)(b * CC) * HH + y) * WW + X0 + lp;
  bf16x8 afr[4];
#pragma unroll
  for (int t = 0; t < 4; ++t)
#pragma unroll
    for (int j = 0; j < 8; ++j)
      afr[t][j] = f2bf(Abase[(size_t)(t * 32 + lg * 8 + j) * HWSZ]);

  __syncthreads();  // staged tile visible

  // ---- compute: pure ds_read_b128 + MFMA ----------------------------------
  int p1 = (lp + 16 < 21) ? (lp + 16) : 21;
  int cosw0[4], cosw1[4];
#pragma unroll
  for (int t = 0; t < 4; ++t) {
    int co = t * 64 + lg * 16;
    cosw0[t] = co ^ ((lp & 15) << 4);
    cosw1[t] = co ^ ((p1 & 15) << 4);
  }

  f32x4 acc[7][2] = {};
#pragma unroll
  for (int dj = 0; dj < 7; ++dj) {
    int rl = w + dj;  // LDS row for yy = y + dj - 3
    int b0 = (rl * NPOS + lp) << 8;
    int b1 = (rl * NPOS + p1) << 8;
#pragma unroll
    for (int t = 0; t < 4; ++t) {
      bf16x8 v0 = *(const bf16x8*)((const char*)ldsb + (b0 + cosw0[t]));
      bf16x8 v1 = *(const bf16x8*)((const char*)ldsb + (b1 + cosw1[t]));
      acc[dj][0] = __builtin_amdgcn_mfma_f32_16x16x32_bf16(afr[t], v0,
                                                           acc[dj][0], 0, 0, 0);
      acc[dj][1] = __builtin_amdgcn_mfma_f32_16x16x32_bf16(afr[t], v1,
                                                           acc[dj][1], 0, 0, 0);
    }
  }

  // ---- Epilogue: LDS transpose -> dense stores ----------------------------
  // D layout: col = lane&15 (+16*nt) = pos, row = 4*(lane>>4)+reg = x_local.
  __syncthreads();  // all ds_reads of ldsb done; safe to reuse as scratch
  float* sc = (float*)ldsb;  // [49][8][16] f32, col-swizzled by +k (mod 16)
#pragma unroll
  for (int dj = 0; dj < 7; ++dj) {
#pragma unroll
    for (int nt = 0; nt < 2; ++nt) {
      int post = lp + 16 * nt;
#pragma unroll
      for (int r = 0; r < 4; ++r) {
        int xlc = 4 * lg + r;
        int di = post - xlc;
        if (di >= 0 && di <= 6) {
          int k = dj * 7 + di;
          sc[k * 128 + w * 16 + ((xlc + k) & 15)] = acc[dj][nt][r];
        }
      }
    }
  }
  __syncthreads();

  float* ob = out + (size_t)(b * KK) * HWSZ + (size_t)ybase * WW + X0;
#pragma unroll
  for (int i = 0; i < 13; ++i) {
    int e = tid + i * 512;
    if (e < KK * 128) {
      int k = e >> 7;
      int yr = (e >> 4) & 7;
      int px = e & 15;
      float v = sc[k * 128 + yr * 16 + ((px + k) & 15)] * (1.0f / 128.0f);
      v = (v > 0.0f) ? v : 0.1f * v;
      ob[(size_t)k * HWSZ + yr * WW + px] = v;
    }
  }
}

// ---------------- launch ----------------------------------------------------
extern "C" void kernel_launch(void* const* d_in, const int* in_sizes, int n_in,
                              void* d_out, int out_size, void* d_ws,
                              size_t ws_size, hipStream_t stream) {
  const float* tenOne = (const float*)d_in[0];
  const float* tenTwo = (const float*)d_in[1];
  const float* tenFlow = (const float*)d_in[2];

  __hip_bfloat16* two_t = (__hip_bfloat16*)d_ws;  // 58.7 MB (ws is larger)

  transpose_kernel<<<BB * (HWSZ / 32), 256, 0, stream>>>(tenTwo, two_t);
  corr_fused<<<1792, 512, 0, stream>>>(tenOne, two_t, tenFlow,
                                       (float*)d_out);
}